// Round 1
// 282.717 us; speedup vs baseline: 1.0560x; 1.0560x over previous
//
#include <hip/hip_runtime.h>

#define NNODES 50000
#define NEDGES 1600000
#define NB 196        // buckets = dst>>8  (50000/256 -> 0..195)
#define BCAP 10240    // edges per bucket capacity (mean 8163, +20 sigma)

typedef __attribute__((ext_vector_type(8))) short short8;   // 8 x bf16
typedef __attribute__((ext_vector_type(4))) float fp32x4;   // MFMA C/D frag

__device__ __forceinline__ unsigned short f2bf(float f) {   // RNE fp32 -> bf16
    unsigned int u = __float_as_uint(f);
    u += 0x7fffu + ((u >> 16) & 1u);
    return (unsigned short)(u >> 16);
}
__device__ __forceinline__ float bflo(unsigned int p) { return __uint_as_float(p << 16); }
__device__ __forceinline__ float bfhi(unsigned int p) { return __uint_as_float(p & 0xffff0000u); }

// ---------------------------------------------------------------------------
// Cast + transpose W (128x128 fp32, k-major) -> WT bf16 (n-major).
// Also zeroes gcur (replaces a memset dispatch; runs before pass1 in-stream).
// ---------------------------------------------------------------------------
__global__ __launch_bounds__(128) void cast_wt(
    const float* __restrict__ WQ, const float* __restrict__ WK,
    const float* __restrict__ WV, unsigned short* __restrict__ WT,
    int* __restrict__ gcur)
{
    if (blockIdx.x == 0) {
        gcur[threadIdx.x] = 0;
        gcur[threadIdx.x + 128] = 0;
    }
    const int w = blockIdx.x >> 7;
    const int n = blockIdx.x & 127;
    const int k = threadIdx.x;
    const float* W = (w == 0) ? WQ : ((w == 1) ? WK : WV);
    WT[w * 16384 + n * 128 + k] = f2bf(W[k * 128 + n]);
}

// ---------------------------------------------------------------------------
// Fused QKV projection, bf16 MFMA 16x16x32, fp32 state read + in-register
// cast. Outputs: Qb [n][128] bf16, KVb [n][256] bf16 (K cols 0..127, V cols
// 128..255). Epilogue: bias add + LDS transpose -> coalesced bf16x8 stores.
// ---------------------------------------------------------------------------
__global__ __launch_bounds__(256) void proj_mfma(
    const float* __restrict__ state, const unsigned short* __restrict__ WT,
    const float* __restrict__ bQ, const float* __restrict__ bK,
    const float* __restrict__ bV,
    unsigned short* __restrict__ Qb, unsigned short* __restrict__ KVb)
{
    __shared__ float lbuf[4][16 * 132];

    const int tid  = threadIdx.x;
    const int wv   = tid >> 6;
    const int lane = tid & 63;
    const int lm   = lane & 15;    // A row / B col / C col within tile
    const int quad = lane >> 4;    // k-chunk select, C row group
    const int m0   = blockIdx.x * 64 + wv * 16;
    const int m    = m0 + lm;

    fp32x4 acc[3][8];
#pragma unroll
    for (int w = 0; w < 3; ++w)
#pragma unroll
        for (int t = 0; t < 8; ++t)
            acc[w][t] = (fp32x4){0.f, 0.f, 0.f, 0.f};

    const int kq = quad * 8;
#pragma unroll
    for (int kb = 0; kb < 128; kb += 32) {
        short8 a = (short8){0,0,0,0,0,0,0,0};
        if (m < NNODES) {
            const float4 f0 = *(const float4*)(state + (size_t)m * 128 + kb + kq);
            const float4 f1 = *(const float4*)(state + (size_t)m * 128 + kb + kq + 4);
            a[0] = (short)f2bf(f0.x); a[1] = (short)f2bf(f0.y);
            a[2] = (short)f2bf(f0.z); a[3] = (short)f2bf(f0.w);
            a[4] = (short)f2bf(f1.x); a[5] = (short)f2bf(f1.y);
            a[6] = (short)f2bf(f1.z); a[7] = (short)f2bf(f1.w);
        }
#pragma unroll
        for (int w = 0; w < 3; ++w) {
#pragma unroll
            for (int t = 0; t < 8; ++t) {
                const short8 b = *(const short8*)(WT + w * 16384 + (t * 16 + lm) * 128 + kb + kq);
                acc[w][t] = __builtin_amdgcn_mfma_f32_16x16x32_bf16(a, b, acc[w][t], 0, 0, 0);
            }
        }
    }

    const int rrow = lane >> 2;          // 0..15
    const int rcol = (lane & 3) * 32;    // 0,32,64,96
    const int grow = m0 + rrow;
#pragma unroll
    for (int w = 0; w < 3; ++w) {
        const float* bp = (w == 0) ? bQ : ((w == 1) ? bK : bV);
        float* L = &lbuf[wv][0];
#pragma unroll
        for (int t = 0; t < 8; ++t) {
            const float bb = bp[t * 16 + lm];
#pragma unroll
            for (int r = 0; r < 4; ++r)
                L[(quad * 4 + r) * 132 + t * 16 + lm] = acc[w][t][r] + bb;
        }
        __syncthreads();
        if (grow < NNODES) {
            unsigned short* gp;
            if (w == 0)      gp = Qb  + (size_t)grow * 128 + rcol;
            else if (w == 1) gp = KVb + (size_t)grow * 256 + rcol;
            else             gp = KVb + (size_t)grow * 256 + 128 + rcol;
#pragma unroll
            for (int c = 0; c < 4; ++c) {
                const float* lp = &L[rrow * 132 + rcol + c * 8];   // 16B aligned
                const float4 x0 = *(const float4*)(lp);
                const float4 x1 = *(const float4*)(lp + 4);
                short8 r;
                r[0] = (short)f2bf(x0.x); r[1] = (short)f2bf(x0.y);
                r[2] = (short)f2bf(x0.z); r[3] = (short)f2bf(x0.w);
                r[4] = (short)f2bf(x1.x); r[5] = (short)f2bf(x1.y);
                r[6] = (short)f2bf(x1.z); r[7] = (short)f2bf(x1.w);
                *(short8*)(gp + c * 8) = r;
            }
        }
        __syncthreads();
    }
}

// ---------------------------------------------------------------------------
// Counting-sort pass 1: bucket edges by dst>>8. 2048 edges/block, SoA
// staging (dst,src separate), LDS hist + scan, ~<=196 global atomics/block,
// bucket-grouped coalesced-run writes into dbuf/sbuf.
// ---------------------------------------------------------------------------
__global__ __launch_bounds__(256) void bucket_pass1(
    const int* __restrict__ src, const int* __restrict__ dst,
    int* __restrict__ gcur, int* __restrict__ dbuf, int* __restrict__ sbuf)
{
    __shared__ int hist[256];
    __shared__ int lofs[256];
    __shared__ int gbase[256];
    __shared__ int stot;
    __shared__ int dstg[2048];
    __shared__ int srcg[2048];

    const int t = threadIdx.x;
    hist[t] = 0;
    __syncthreads();

    const long long e0 = (long long)blockIdx.x * 2048 + t * 8;
    const bool valid = (e0 < NEDGES);
    int4 sA, sB, dA, dB;
    int b[8], r[8];
    if (valid) {
        sA = *(const int4*)(src + e0);     sB = *(const int4*)(src + e0 + 4);
        dA = *(const int4*)(dst + e0);     dB = *(const int4*)(dst + e0 + 4);
        const int dd[8] = {dA.x, dA.y, dA.z, dA.w, dB.x, dB.y, dB.z, dB.w};
#pragma unroll
        for (int j = 0; j < 8; ++j) {
            b[j] = dd[j] >> 8;
            r[j] = atomicAdd(&hist[b[j]], 1);
        }
    }
    __syncthreads();

    const int v = hist[t];
    lofs[t] = v;
    __syncthreads();
    for (int off = 1; off < 256; off <<= 1) {
        const int y = (t >= off) ? lofs[t - off] : 0;
        __syncthreads();
        lofs[t] += y;
        __syncthreads();
    }
    if (t == 255) stot = lofs[255];
    if (t < NB && v > 0) gbase[t] = atomicAdd(&gcur[t], v);
    __syncthreads();
    lofs[t] -= v;                 // exclusive
    __syncthreads();

    if (valid) {
        const int dd[8] = {dA.x, dA.y, dA.z, dA.w, dB.x, dB.y, dB.z, dB.w};
        const int ss[8] = {sA.x, sA.y, sA.z, sA.w, sB.x, sB.y, sB.z, sB.w};
#pragma unroll
        for (int j = 0; j < 8; ++j) {
            const int p = lofs[b[j]] + r[j];
            dstg[p] = dd[j];
            srcg[p] = ss[j];
        }
    }
    __syncthreads();

    const int tot = stot;
#pragma unroll
    for (int j = 0; j < 8; ++j) {
        const int slot = t + 256 * j;
        if (slot < tot) {
            const int dd = dstg[slot];
            const int bb = dd >> 8;
            const long long g = (long long)bb * BCAP + gbase[bb] + (slot - lofs[bb]);
            dbuf[g] = dd;
            sbuf[g] = srcg[slot];
        }
    }
}

// ---------------------------------------------------------------------------
// Counting-sort pass 2: one block per bucket. 1024 threads (16 waves/CU vs 4
// before -- this kernel is latency-bound at grid=196 blocks, so wave count is
// the lever). LDS hist + low-byte staging (dstb) so the grouping pass reads
// LDS instead of re-reading dbuf from global. Scan runs on first 256 threads.
// ---------------------------------------------------------------------------
__global__ __launch_bounds__(1024) void bucket_pass2(
    const int* __restrict__ dbuf, const int* __restrict__ sbuf,
    const int* __restrict__ gcur, int* __restrict__ eidx, int2* __restrict__ offs2)
{
    __shared__ int hist[256];
    __shared__ int lofs[256];
    __shared__ int cur[256];
    __shared__ int srcbuf[BCAP];            // 40 KB
    __shared__ unsigned char dstb[BCAP];    // 10 KB (low byte of dst per edge)

    const int b = blockIdx.x;
    const int t = threadIdx.x;
    int cnt = gcur[b];
    if (cnt > BCAP) cnt = BCAP;
    const long long base = (long long)b * BCAP;

    if (t < 256) hist[t] = 0;
    __syncthreads();

    for (int i = t; i < cnt; i += 1024) {
        const int d = dbuf[base + i] & 255;
        dstb[i] = (unsigned char)d;
        atomicAdd(&hist[d], 1);
    }
    __syncthreads();

    int v = 0;
    if (t < 256) { v = hist[t]; lofs[t] = v; }
    __syncthreads();
    for (int off = 1; off < 256; off <<= 1) {
        int y = 0;
        if (t < 256 && t >= off) y = lofs[t - off];
        __syncthreads();
        if (t < 256) lofs[t] += y;
        __syncthreads();
    }
    if (t < 256) {
        const int ex = lofs[t] - v;          // exclusive
        cur[t] = ex;
        const int n = b * 256 + t;
        if (n < NNODES) {
            int2 oe; oe.x = (int)(base + ex); oe.y = (int)(base + ex + v);
            offs2[n] = oe;
        }
    }
    __syncthreads();

    for (int i = t; i < cnt; i += 1024) {
        const int d = dstb[i];
        const int p = atomicAdd(&cur[d], 1);
        srcbuf[p] = sbuf[base + i];
    }
    __syncthreads();

    for (int i = t; i < cnt; i += 1024)
        eidx[base + i] = srcbuf[i];
}

// ---------------------------------------------------------------------------
// Aggregation: one wave per dst node; lane = (edge-slot eo=l>>3, head h=l&7).
// 16 edges/iteration: 8 independent dwordx4 KV loads + pipelined eidx loads.
// The eidx gather is prefetched one iteration ahead so the KV gathers for the
// current iteration issue immediately from registers (breaks the
// eidx->KV-address dependent-latency chain; the round-0 kernel serialized
// lat(eidx)+lat(KV) every iteration). Q is pre-scaled by 1/sqrt(D)=0.25
// (exact pow2) so the score scale costs nothing per edge.
// Masked slots alias eidx[beg] (hot line, VALU-only waste).
// ---------------------------------------------------------------------------
__global__ __launch_bounds__(256) void aggregate_kernel(
    const int* __restrict__ eidx, const int2* __restrict__ offs2,
    const unsigned short* __restrict__ Qb, const unsigned short* __restrict__ KVb,
    float* __restrict__ out)
{
    const int n = blockIdx.x * 4 + (threadIdx.x >> 6);
    const int l = threadIdx.x & 63;
    if (n >= NNODES) return;
    const int eo = l >> 3;       // edge slot 0..7
    const int h  = l & 7;        // head 0..7

    const int2 oe = offs2[n];
    const int beg = oe.x, end = oe.y;

    // prefetch first iteration's indices before anything else
    const int pi0 = beg + eo;
    const int pi1 = pi0 + 8;
    int s0 = eidx[(pi0 < end) ? pi0 : beg];
    int s1 = eidx[(pi1 < end) ? pi1 : beg];

    const unsigned short* qp = Qb + (size_t)n * 128 + h * 16;
    const uint4 qa = *(const uint4*)(qp);
    const uint4 qc = *(const uint4*)(qp + 8);
    float q[16];
    q[0]  = bflo(qa.x); q[1]  = bfhi(qa.x); q[2]  = bflo(qa.y); q[3]  = bfhi(qa.y);
    q[4]  = bflo(qa.z); q[5]  = bfhi(qa.z); q[6]  = bflo(qa.w); q[7]  = bfhi(qa.w);
    q[8]  = bflo(qc.x); q[9]  = bfhi(qc.x); q[10] = bflo(qc.y); q[11] = bfhi(qc.y);
    q[12] = bflo(qc.z); q[13] = bfhi(qc.z); q[14] = bflo(qc.w); q[15] = bfhi(qc.w);
#pragma unroll
    for (int j = 0; j < 16; ++j) q[j] *= 0.25f;   // fold 1/sqrt(16): exact pow2

    float acc[16];
#pragma unroll
    for (int j = 0; j < 16; ++j) acc[j] = 0.f;
    float zacc = 0.f;

    for (int i = beg; i < end; i += 16) {
        const bool act0 = (i + eo < end);
        const bool act1 = (i + eo + 8 < end);
        const int cs0 = s0;
        const int cs1 = s1;

        // issue next iteration's index gathers now; they complete under the
        // KV-load + dot-chain latency of this iteration
        const int ni0 = i + 16 + eo;
        const int ni1 = ni0 + 8;
        s0 = eidx[(ni0 < end) ? ni0 : beg];
        s1 = eidx[(ni1 < end) ? ni1 : beg];

        const unsigned short* kp0 = KVb + (size_t)cs0 * 256 + h * 16;
        const unsigned short* kp1 = KVb + (size_t)cs1 * 256 + h * 16;
        const uint4 ka0 = *(const uint4*)(kp0);
        const uint4 kc0 = *(const uint4*)(kp0 + 8);
        const uint4 va0 = *(const uint4*)(kp0 + 128);
        const uint4 vc0 = *(const uint4*)(kp0 + 136);
        const uint4 ka1 = *(const uint4*)(kp1);
        const uint4 kc1 = *(const uint4*)(kp1 + 8);
        const uint4 va1 = *(const uint4*)(kp1 + 128);
        const uint4 vc1 = *(const uint4*)(kp1 + 136);

        float p0;
        p0 = fmaf(bfhi(ka0.x), q[1],  bflo(ka0.x) * q[0]);
        p0 = fmaf(bflo(ka0.y), q[2],  p0); p0 = fmaf(bfhi(ka0.y), q[3],  p0);
        p0 = fmaf(bflo(ka0.z), q[4],  p0); p0 = fmaf(bfhi(ka0.z), q[5],  p0);
        p0 = fmaf(bflo(ka0.w), q[6],  p0); p0 = fmaf(bfhi(ka0.w), q[7],  p0);
        p0 = fmaf(bflo(kc0.x), q[8],  p0); p0 = fmaf(bfhi(kc0.x), q[9],  p0);
        p0 = fmaf(bflo(kc0.y), q[10], p0); p0 = fmaf(bfhi(kc0.y), q[11], p0);
        p0 = fmaf(bflo(kc0.z), q[12], p0); p0 = fmaf(bfhi(kc0.z), q[13], p0);
        p0 = fmaf(bflo(kc0.w), q[14], p0); p0 = fmaf(bfhi(kc0.w), q[15], p0);

        float p1;
        p1 = fmaf(bfhi(ka1.x), q[1],  bflo(ka1.x) * q[0]);
        p1 = fmaf(bflo(ka1.y), q[2],  p1); p1 = fmaf(bfhi(ka1.y), q[3],  p1);
        p1 = fmaf(bflo(ka1.z), q[4],  p1); p1 = fmaf(bfhi(ka1.z), q[5],  p1);
        p1 = fmaf(bflo(ka1.w), q[6],  p1); p1 = fmaf(bfhi(ka1.w), q[7],  p1);
        p1 = fmaf(bflo(kc1.x), q[8],  p1); p1 = fmaf(bfhi(kc1.x), q[9],  p1);
        p1 = fmaf(bflo(kc1.y), q[10], p1); p1 = fmaf(bfhi(kc1.y), q[11], p1);
        p1 = fmaf(bflo(kc1.z), q[12], p1); p1 = fmaf(bfhi(kc1.z), q[13], p1);
        p1 = fmaf(bflo(kc1.w), q[14], p1); p1 = fmaf(bfhi(kc1.w), q[15], p1);

        float w0 = __expf(fminf(fmaxf(p0, -5.f), 5.f));
        float w1 = __expf(fminf(fmaxf(p1, -5.f), 5.f));
        w0 = act0 ? w0 : 0.f;
        w1 = act1 ? w1 : 0.f;
        zacc += w0 + w1;

        acc[0]  = fmaf(bflo(va0.x), w0, acc[0]);  acc[1]  = fmaf(bfhi(va0.x), w0, acc[1]);
        acc[2]  = fmaf(bflo(va0.y), w0, acc[2]);  acc[3]  = fmaf(bfhi(va0.y), w0, acc[3]);
        acc[4]  = fmaf(bflo(va0.z), w0, acc[4]);  acc[5]  = fmaf(bfhi(va0.z), w0, acc[5]);
        acc[6]  = fmaf(bflo(va0.w), w0, acc[6]);  acc[7]  = fmaf(bfhi(va0.w), w0, acc[7]);
        acc[8]  = fmaf(bflo(vc0.x), w0, acc[8]);  acc[9]  = fmaf(bfhi(vc0.x), w0, acc[9]);
        acc[10] = fmaf(bflo(vc0.y), w0, acc[10]); acc[11] = fmaf(bfhi(vc0.y), w0, acc[11]);
        acc[12] = fmaf(bflo(vc0.z), w0, acc[12]); acc[13] = fmaf(bfhi(vc0.z), w0, acc[13]);
        acc[14] = fmaf(bflo(vc0.w), w0, acc[14]); acc[15] = fmaf(bfhi(vc0.w), w0, acc[15]);

        acc[0]  = fmaf(bflo(va1.x), w1, acc[0]);  acc[1]  = fmaf(bfhi(va1.x), w1, acc[1]);
        acc[2]  = fmaf(bflo(va1.y), w1, acc[2]);  acc[3]  = fmaf(bfhi(va1.y), w1, acc[3]);
        acc[4]  = fmaf(bflo(va1.z), w1, acc[4]);  acc[5]  = fmaf(bfhi(va1.z), w1, acc[5]);
        acc[6]  = fmaf(bflo(va1.w), w1, acc[6]);  acc[7]  = fmaf(bfhi(va1.w), w1, acc[7]);
        acc[8]  = fmaf(bflo(vc1.x), w1, acc[8]);  acc[9]  = fmaf(bfhi(vc1.x), w1, acc[9]);
        acc[10] = fmaf(bflo(vc1.y), w1, acc[10]); acc[11] = fmaf(bfhi(vc1.y), w1, acc[11]);
        acc[12] = fmaf(bflo(vc1.z), w1, acc[12]); acc[13] = fmaf(bfhi(vc1.z), w1, acc[13]);
        acc[14] = fmaf(bflo(vc1.w), w1, acc[14]); acc[15] = fmaf(bfhi(vc1.w), w1, acc[15]);
    }

    // reduce across edge slots (lanes differing in bits 3..5)
#pragma unroll
    for (int st = 8; st < 64; st <<= 1) {
        zacc += __shfl_xor(zacc, st);
#pragma unroll
        for (int j = 0; j < 16; ++j) acc[j] += __shfl_xor(acc[j], st);
    }

    if (eo == 0) {
        const float inv = 1.0f / zacc;
        float* op = out + (size_t)n * 128 + h * 16;
        *(float4*)(op)      = make_float4(acc[0]*inv,  acc[1]*inv,  acc[2]*inv,  acc[3]*inv);
        *(float4*)(op + 4)  = make_float4(acc[4]*inv,  acc[5]*inv,  acc[6]*inv,  acc[7]*inv);
        *(float4*)(op + 8)  = make_float4(acc[8]*inv,  acc[9]*inv,  acc[10]*inv, acc[11]*inv);
        *(float4*)(op + 12) = make_float4(acc[12]*inv, acc[13]*inv, acc[14]*inv, acc[15]*inv);
    }
}

extern "C" void kernel_launch(void* const* d_in, const int* in_sizes, int n_in,
                              void* d_out, int out_size, void* d_ws, size_t ws_size,
                              hipStream_t stream)
{
    const float* state = (const float*)d_in[0];
    const int*   src   = (const int*)d_in[1];
    const int*   dst   = (const int*)d_in[2];
    const float* WQ    = (const float*)d_in[3];
    const float* bQ    = (const float*)d_in[4];
    const float* WK    = (const float*)d_in[5];
    const float* bK    = (const float*)d_in[6];
    const float* WV    = (const float*)d_in[7];
    const float* bV    = (const float*)d_in[8];
    float* out = (float*)d_out;

    unsigned short* Qb  = (unsigned short*)d_ws;                 // 12.8 MB
    unsigned short* KVb = Qb + (size_t)NNODES * 128;             // 25.6 MB
    unsigned short* WT  = KVb + (size_t)NNODES * 256;            // 96 KB
    int* dbuf  = (int*)(WT + 3 * 16384);                         // NB*BCAP*4B
    int* sbuf  = dbuf + (size_t)NB * BCAP;
    int* eidx  = sbuf + (size_t)NB * BCAP;
    int* gcur  = eidx + (size_t)NB * BCAP;                       // 256
    int2* offs2 = (int2*)(gcur + 256);                           // 50000 int2

    cast_wt<<<3 * 128, 128, 0, stream>>>(WQ, WK, WV, WT, gcur);
    proj_mfma<<<(NNODES + 63) / 64, 256, 0, stream>>>(state, WT, bQ, bK, bV, Qb, KVb);

    bucket_pass1<<<(NEDGES + 2047) / 2048, 256, 0, stream>>>(src, dst, gcur, dbuf, sbuf);
    bucket_pass2<<<NB, 1024, 0, stream>>>(dbuf, sbuf, gcur, eidx, offs2);

    aggregate_kernel<<<(NNODES + 3) / 4, 256, 0, stream>>>(eidx, offs2, Qb, KVb, out);
}